// Round 3
// baseline (1648.986 us; speedup 1.0000x reference)
//
#include <hip/hip_runtime.h>
#include <hip/hip_bf16.h>
#include <math.h>

typedef __bf16 bf16_t;
typedef float f32x4 __attribute__((ext_vector_type(4)));
typedef __bf16 bf16x8 __attribute__((ext_vector_type(8)));
typedef int i32x4 __attribute__((ext_vector_type(4)));

#define SCALING 0.17677669529663687f
#define LNEPS 1e-5f

// ws layout (bytes); total = 222,953,476 (vt lives in d_out)
#define OFF_QKG  0u            // bf16 [131072][768]: q | k | gate; q-region reused for gated AV out
#define OFF_LOG  201326592u    // f32  [8][512][512]: attn logits
#define OFF_BIAS 209715200u    // f32  [8][512][512]: pair bias
#define OFF_P    218103808u    // bf16 [8][512][512]: softmax probs
#define OFF_WT   222298112u    // bf16 [1024][256]  : [wq|wk|wv|wg]^T
#define OFF_WTO  222822400u    // bf16 [256][256]   : w_out^T
#define OFF_FLAG 222953472u    // int: 1 if inputs are fp32, 0 if bf16

static __device__ __forceinline__ f32x4 mfma16(bf16x8 a, bf16x8 b, f32x4 c) {
  return __builtin_amdgcn_mfma_f32_16x16x32_bf16(a, b, c, 0, 0, 0);
}

// dual-dtype scalar load of logical element i
static __device__ __forceinline__ float ldf(const void* p, int i, int is32) {
  return is32 ? ((const float*)p)[i] : (float)((const bf16_t*)p)[i];
}
static __device__ __forceinline__ float scrubf(float x) {
  if (x != x) return 0.f;
  return fminf(fmaxf(x, -3.3e38f), 3.3e38f);
}
// nan_to_num on packed 8x bf16
static __device__ __forceinline__ i32x4 scrub8(i32x4 v) {
  short* sp = (short*)&v;
#pragma unroll
  for (int e = 0; e < 8; e++) {
    int u = sp[e] & 0x7FFF;
    if (u > 0x7F80) sp[e] = 0;
    else if (u == 0x7F80) sp[e] = (short)((sp[e] & 0x8000) | 0x7F7F);
  }
  return v;
}

// ---------------- K-1: detect input dtype ----------------
__global__ __launch_bounds__(256) void k_detect(const unsigned short* raw, int* flag) {
  __shared__ int s;
  int t = threadIdx.x;
  if (t == 0) s = 0;
  __syncthreads();
  int local = 0;
  for (int i = 0; i < 16; i++) {
    unsigned short u = raw[t * 16 + i];
    int e = (u >> 7) & 0xFF;
    if (e >= 170) local = 1;   // |x| >= 2^43 as bf16: impossible for N(0,1) bf16 data
  }
  if (local) s = 1;
  __syncthreads();
  if (t == 0) *flag = s;
}

// ---------------- K0: transpose weights (any dtype -> bf16) ----------------
__global__ __launch_bounds__(256) void k_transpose(
    const void* wq, const void* wk, const void* wv, const void* wg,
    const void* wout, const int* flag, bf16_t* wt_cat, bf16_t* wt_out) {
  int is32 = *flag;
  int idx = blockIdx.x * 256 + threadIdx.x;
  if (idx < 1024 * 256) {
    int c = idx >> 8, k = idx & 255;
    const void* src = (c < 256) ? wq : (c < 512) ? wk : (c < 768) ? wv : wg;
    wt_cat[c * 256 + k] = (bf16_t)ldf(src, k * 256 + (c & 255), is32);
  } else {
    int i2 = idx - 1024 * 256;  // < 65536
    int c = i2 >> 8, k = i2 & 255;
    wt_out[c * 256 + k] = (bf16_t)ldf(wout, k * 256 + c, is32);
  }
}

// ---------------- K1: pair LN + @ w_b -> bias[h][q][k] (f32) ----------------
__global__ __launch_bounds__(256) void k_pair_bias(
    const void* pair, const void* g, const void* b,
    const void* wb, const int* flag, float* bias_ws) {
  int is32 = *flag;
  int lane = threadIdx.x & 63;
  int w = threadIdx.x >> 6;
  int row = blockIdx.x * 4 + w;  // (qp*512 + kp), 0..262143
  float x0 = scrubf(ldf(pair, row * 128 + 2 * lane, is32));
  float x1 = scrubf(ldf(pair, row * 128 + 2 * lane + 1, is32));
  float s = x0 + x1, sq = x0 * x0 + x1 * x1;
#pragma unroll
  for (int o = 32; o >= 1; o >>= 1) {
    s += __shfl_xor(s, o, 64);
    sq += __shfl_xor(sq, o, 64);
  }
  float mu = s * (1.f / 128.f);
  float var = sq * (1.f / 128.f) - mu * mu;
  float rs = rsqrtf(fmaxf(var, 0.f) + LNEPS);
  float xn0 = (x0 - mu) * rs * ldf(g, 2 * lane, is32) + ldf(b, 2 * lane, is32);
  float xn1 = (x1 - mu) * rs * ldf(g, 2 * lane + 1, is32) + ldf(b, 2 * lane + 1, is32);
  float ph[8];
#pragma unroll
  for (int hh = 0; hh < 8; hh++)
    ph[hh] = xn0 * ldf(wb, (2 * lane) * 8 + hh, is32) + xn1 * ldf(wb, (2 * lane + 1) * 8 + hh, is32);
#pragma unroll
  for (int o = 32; o >= 1; o >>= 1) {
#pragma unroll
    for (int hh = 0; hh < 8; hh++) ph[hh] += __shfl_xor(ph[hh], o, 64);
  }
  if (lane == 0) {
    int qp = row >> 9, kp = row & 511;
    float* bp = bias_ws + (size_t)qp * 512 + kp;
#pragma unroll
    for (int hh = 0; hh < 8; hh++) bp[(size_t)hh * 262144] = ph[hh];
  }
}

// ---------------- K2: msa LN + QKVG projection GEMM ----------------
__global__ __launch_bounds__(256) void k_lnproj(
    const void* msa, const void* lng, const void* lnb,
    const bf16_t* wt_cat, const void* bg, const int* mask, const int* flag,
    bf16_t* qkg, bf16_t* vt) {
  __shared__ bf16_t As[64 * 264];
  __shared__ bf16_t Bs[64 * 72];
  int is32 = *flag;
  int t = threadIdx.x;
  int bm = blockIdx.x >> 4, bn = blockIdx.x & 15;
  int row0 = bm * 64;
  // stage A: 64 rows x 256 cols, converting to bf16 with nan_to_num
  if (is32) {
#pragma unroll
    for (int i = 0; i < 16; i++) {
      int flat = t + i * 256;            // 4096 chunks of 4 floats
      int r = flat >> 6, c4 = flat & 63;
      f32x4 v = *(const f32x4*)((const float*)msa + (size_t)(row0 + r) * 256 + c4 * 4);
      bf16_t* dst = As + r * 264 + c4 * 4;
      dst[0] = (bf16_t)scrubf(v[0]);
      dst[1] = (bf16_t)scrubf(v[1]);
      dst[2] = (bf16_t)scrubf(v[2]);
      dst[3] = (bf16_t)scrubf(v[3]);
    }
  } else {
#pragma unroll
    for (int i = 0; i < 8; i++) {
      int flat = t + i * 256;            // 2048 chunks of 8 bf16
      int r = flat >> 5, c8 = flat & 31;
      i32x4 v = *(const i32x4*)((const bf16_t*)msa + (size_t)(row0 + r) * 256 + c8 * 8);
      *(i32x4*)(As + r * 264 + c8 * 8) = scrub8(v);
    }
  }
  __syncthreads();
  // LN: 16 rows per wave
  int lane = t & 63, w = t >> 6;
  float gv0 = ldf(lng, lane * 4, is32), gv1 = ldf(lng, lane * 4 + 1, is32);
  float gv2 = ldf(lng, lane * 4 + 2, is32), gv3 = ldf(lng, lane * 4 + 3, is32);
  float bv0 = ldf(lnb, lane * 4, is32), bv1 = ldf(lnb, lane * 4 + 1, is32);
  float bv2 = ldf(lnb, lane * 4 + 2, is32), bv3 = ldf(lnb, lane * 4 + 3, is32);
  for (int rr = 0; rr < 16; rr++) {
    int r = w * 16 + rr;
    bf16_t* ap = As + r * 264 + lane * 4;
    float x0 = (float)ap[0], x1 = (float)ap[1], x2 = (float)ap[2], x3 = (float)ap[3];
    float s = x0 + x1 + x2 + x3;
    float sq = x0 * x0 + x1 * x1 + x2 * x2 + x3 * x3;
#pragma unroll
    for (int o = 32; o >= 1; o >>= 1) {
      s += __shfl_xor(s, o, 64);
      sq += __shfl_xor(sq, o, 64);
    }
    float mu = s * (1.f / 256.f);
    float var = sq * (1.f / 256.f) - mu * mu;
    float rsv = rsqrtf(fmaxf(var, 0.f) + LNEPS);
    ap[0] = (bf16_t)((x0 - mu) * rsv * gv0 + bv0);
    ap[1] = (bf16_t)((x1 - mu) * rsv * gv1 + bv1);
    ap[2] = (bf16_t)((x2 - mu) * rsv * gv2 + bv2);
    ap[3] = (bf16_t)((x3 - mu) * rsv * gv3 + bv3);
  }
  __syncthreads();

  f32x4 z = {0.f, 0.f, 0.f, 0.f};
  f32x4 acc[2][2] = {{z, z}, {z, z}};
  int mw = w & 1, nw = w >> 1;
  for (int kt = 0; kt < 4; kt++) {
#pragma unroll
    for (int i = 0; i < 2; i++) {
      int flat = t + i * 256;  // 512 chunks
      int r = flat >> 3, c8 = flat & 7;
      i32x4 v = *(const i32x4*)(wt_cat + (size_t)(bn * 64 + r) * 256 + kt * 64 + c8 * 8);
      *(i32x4*)(Bs + r * 72 + c8 * 8) = v;
    }
    __syncthreads();
#pragma unroll
    for (int kk = 0; kk < 64; kk += 32) {
      int ko = kt * 64 + kk + (lane >> 4) * 8;
      bf16x8 a0 = *(const bf16x8*)(As + (mw * 32 + (lane & 15)) * 264 + ko);
      bf16x8 a1 = *(const bf16x8*)(As + (mw * 32 + 16 + (lane & 15)) * 264 + ko);
      bf16x8 b0 = *(const bf16x8*)(Bs + (nw * 32 + (lane & 15)) * 72 + kk + (lane >> 4) * 8);
      bf16x8 b1 = *(const bf16x8*)(Bs + (nw * 32 + 16 + (lane & 15)) * 72 + kk + (lane >> 4) * 8);
      acc[0][0] = mfma16(a0, b0, acc[0][0]);
      acc[0][1] = mfma16(a0, b1, acc[0][1]);
      acc[1][0] = mfma16(a1, b0, acc[1][0]);
      acc[1][1] = mfma16(a1, b1, acc[1][1]);
    }
    __syncthreads();
  }
  // epilogue
  int quad = lane >> 4, cl = lane & 15;
#pragma unroll
  for (int mt = 0; mt < 2; mt++) {
#pragma unroll
    for (int nt = 0; nt < 2; nt++) {
      int col = bn * 64 + nw * 32 + nt * 16 + cl;  // region uniform per block
      int region = col >> 8;
#pragma unroll
      for (int i = 0; i < 4; i++) {
        int r = row0 + mw * 32 + mt * 16 + quad * 4 + i;
        int l = r & 511;
        bool pad = (mask[l] == 0);
        float v = acc[mt][nt][i];
        if (region == 0) {                       // q
          qkg[(size_t)r * 768 + col] = (bf16_t)(pad ? 0.f : v);
        } else if (region == 1) {                // k (scaled)
          qkg[(size_t)r * 768 + col] = (bf16_t)(pad ? 0.f : v * SCALING);
        } else if (region == 2) {                // v -> vt[(n*8+h)*32+d][l]
          int hd = col - 512;
          int n = r >> 9;
          vt[((size_t)((n * 8 + (hd >> 5)) * 32 + (hd & 31))) * 512 + l] =
              (bf16_t)(pad ? 0.f : v);
        } else {                                 // gate = sigmoid(x + b_g)
          float x = v + ldf(bg, col - 768, is32);
          qkg[(size_t)r * 768 + 512 + (col - 768)] = (bf16_t)(1.f / (1.f + __expf(-x)));
        }
      }
    }
  }
}

// ---------------- K3: logits[h][q][k] = sum_{n,d} q*k ----------------
__global__ __launch_bounds__(256) void k_logits(const bf16_t* qkg, float* logit_ws) {
  __shared__ bf16_t As[64 * 136];
  __shared__ bf16_t Bs[64 * 136];
  int t = threadIdx.x, lane = t & 63, w = t >> 6;
  int ktile = blockIdx.x & 7, qtile = (blockIdx.x >> 3) & 7, h = blockIdx.x >> 6;
  int mw = w & 1, nw = w >> 1;
  f32x4 z = {0.f, 0.f, 0.f, 0.f};
  f32x4 acc[2][2] = {{z, z}, {z, z}};
  for (int s = 0; s < 64; s++) {
    int kk0 = s * 128;
#pragma unroll
    for (int i = 0; i < 4; i++) {
      int flat = t + i * 256;  // 1024 chunks
      int r = flat >> 4, c8 = flat & 15;
      int kk = kk0 + c8 * 8;
      int n = kk >> 5, d = kk & 31;
      i32x4 va = *(const i32x4*)(qkg + ((size_t)(n * 512 + qtile * 64 + r)) * 768 + h * 32 + d);
      *(i32x4*)(As + r * 136 + c8 * 8) = va;
      i32x4 vb = *(const i32x4*)(qkg + ((size_t)(n * 512 + ktile * 64 + r)) * 768 + 256 + h * 32 + d);
      *(i32x4*)(Bs + r * 136 + c8 * 8) = vb;
    }
    __syncthreads();
#pragma unroll
    for (int kk = 0; kk < 128; kk += 32) {
      int ko = kk + (lane >> 4) * 8;
      bf16x8 a0 = *(const bf16x8*)(As + (mw * 32 + (lane & 15)) * 136 + ko);
      bf16x8 a1 = *(const bf16x8*)(As + (mw * 32 + 16 + (lane & 15)) * 136 + ko);
      bf16x8 b0 = *(const bf16x8*)(Bs + (nw * 32 + (lane & 15)) * 136 + ko);
      bf16x8 b1 = *(const bf16x8*)(Bs + (nw * 32 + 16 + (lane & 15)) * 136 + ko);
      acc[0][0] = mfma16(a0, b0, acc[0][0]);
      acc[0][1] = mfma16(a0, b1, acc[0][1]);
      acc[1][0] = mfma16(a1, b0, acc[1][0]);
      acc[1][1] = mfma16(a1, b1, acc[1][1]);
    }
    __syncthreads();
  }
  int quad = lane >> 4, cl = lane & 15;
#pragma unroll
  for (int mt = 0; mt < 2; mt++) {
#pragma unroll
    for (int nt = 0; nt < 2; nt++) {
      int kp = ktile * 64 + nw * 32 + nt * 16 + cl;
#pragma unroll
      for (int i = 0; i < 4; i++) {
        int q = qtile * 64 + mw * 32 + mt * 16 + quad * 4 + i;
        logit_ws[((size_t)(h * 512 + q)) * 512 + kp] = acc[mt][nt][i];
      }
    }
  }
}

// ---------------- K4: softmax over k with bias + 2D mask ----------------
__global__ __launch_bounds__(256) void k_softmax(
    const float* logit_ws, const float* bias_ws, const int* mask, bf16_t* p_ws) {
  __shared__ float red[8];
  int t = threadIdx.x;
  int hq = blockIdx.x;  // h*512 + q
  int q = hq & 511;
  bool padq = (mask[q] == 0);
  const float* lg = logit_ws + (size_t)hq * 512;
  const float* bi = bias_ws + (size_t)(hq >> 9) * 262144 + (size_t)q * 512;
  int k0 = t * 2;
  float v0 = lg[k0] + bi[k0];
  float v1 = lg[k0 + 1] + bi[k0 + 1];
  if (padq || mask[k0] == 0) v0 = -1e9f;
  if (padq || mask[k0 + 1] == 0) v1 = -1e9f;
  float m = fmaxf(v0, v1);
#pragma unroll
  for (int o = 32; o >= 1; o >>= 1) m = fmaxf(m, __shfl_xor(m, o, 64));
  if ((t & 63) == 0) red[t >> 6] = m;
  __syncthreads();
  m = fmaxf(fmaxf(red[0], red[1]), fmaxf(red[2], red[3]));
  float e0 = __expf(v0 - m), e1 = __expf(v1 - m);
  float s = e0 + e1;
#pragma unroll
  for (int o = 32; o >= 1; o >>= 1) s += __shfl_xor(s, o, 64);
  if ((t & 63) == 0) red[4 + (t >> 6)] = s;
  __syncthreads();
  s = red[4] + red[5] + red[6] + red[7];
  float inv = 1.f / s;
  p_ws[(size_t)hq * 512 + k0] = (bf16_t)(e0 * inv);
  p_ws[(size_t)hq * 512 + k0 + 1] = (bf16_t)(e1 * inv);
}

// ---------------- K5: O = P @ V, * gate -> q-region of qkg ----------------
__global__ __launch_bounds__(256) void k_av(
    const bf16_t* p_ws, const bf16_t* vt, bf16_t* qkg) {
  __shared__ bf16_t Ps[64 * 136];
  __shared__ bf16_t Vs[32 * 136];
  int t = threadIdx.x, lane = t & 63, w = t >> 6;
  int n = blockIdx.x & 255;
  int rest = blockIdx.x >> 8;
  int qt = rest & 7, h = rest >> 3;
  f32x4 z = {0.f, 0.f, 0.f, 0.f};
  f32x4 acc[2] = {z, z};
  for (int s = 0; s < 4; s++) {
    int k0 = s * 128;
#pragma unroll
    for (int i = 0; i < 4; i++) {
      int flat = t + i * 256;
      int r = flat >> 4, c8 = flat & 15;
      *(i32x4*)(Ps + r * 136 + c8 * 8) =
          *(const i32x4*)(p_ws + ((size_t)(h * 512 + qt * 64 + r)) * 512 + k0 + c8 * 8);
    }
#pragma unroll
    for (int i = 0; i < 2; i++) {
      int flat = t + i * 256;
      int r = flat >> 4, c8 = flat & 15;  // r = d
      *(i32x4*)(Vs + r * 136 + c8 * 8) =
          *(const i32x4*)(vt + ((size_t)((n * 8 + h) * 32 + r)) * 512 + k0 + c8 * 8);
    }
    __syncthreads();
#pragma unroll
    for (int kk = 0; kk < 128; kk += 32) {
      int ko = kk + (lane >> 4) * 8;
      bf16x8 a = *(const bf16x8*)(Ps + (w * 16 + (lane & 15)) * 136 + ko);
      bf16x8 b0 = *(const bf16x8*)(Vs + ((lane & 15)) * 136 + ko);
      bf16x8 b1 = *(const bf16x8*)(Vs + (16 + (lane & 15)) * 136 + ko);
      acc[0] = mfma16(a, b0, acc[0]);
      acc[1] = mfma16(a, b1, acc[1]);
    }
    __syncthreads();
  }
  int quad = lane >> 4, cl = lane & 15;
#pragma unroll
  for (int nt = 0; nt < 2; nt++) {
#pragma unroll
    for (int i = 0; i < 4; i++) {
      int q = qt * 64 + w * 16 + quad * 4 + i;
      int d = nt * 16 + cl;
      size_t base = ((size_t)(n * 512 + q)) * 768;
      float gate = (float)qkg[base + 512 + h * 32 + d];
      qkg[base + h * 32 + d] = (bf16_t)(acc[nt][i] * gate);
    }
  }
}

// ---------------- K6: out = gated @ w_out + b_out, pad-zeroed ----------------
__global__ __launch_bounds__(256) void k_out(
    const bf16_t* qkg, const bf16_t* wt_out, const void* b_out,
    const int* mask, const int* flag, void* outp) {
  __shared__ bf16_t As[64 * 72];
  __shared__ bf16_t Bs[64 * 72];
  int is32 = *flag;
  int t = threadIdx.x, lane = t & 63, w = t >> 6;
  int bm = blockIdx.x >> 2, bn = blockIdx.x & 3;
  int row0 = bm * 64;
  int mw = w & 1, nw = w >> 1;
  f32x4 z = {0.f, 0.f, 0.f, 0.f};
  f32x4 acc[2][2] = {{z, z}, {z, z}};
  for (int kt = 0; kt < 4; kt++) {
#pragma unroll
    for (int i = 0; i < 2; i++) {
      int flat = t + i * 256;
      int r = flat >> 3, c8 = flat & 7;
      *(i32x4*)(As + r * 72 + c8 * 8) =
          *(const i32x4*)(qkg + (size_t)(row0 + r) * 768 + kt * 64 + c8 * 8);
      *(i32x4*)(Bs + r * 72 + c8 * 8) =
          *(const i32x4*)(wt_out + (size_t)(bn * 64 + r) * 256 + kt * 64 + c8 * 8);
    }
    __syncthreads();
#pragma unroll
    for (int kk = 0; kk < 64; kk += 32) {
      int ko = kk + (lane >> 4) * 8;
      bf16x8 a0 = *(const bf16x8*)(As + (mw * 32 + (lane & 15)) * 72 + ko);
      bf16x8 a1 = *(const bf16x8*)(As + (mw * 32 + 16 + (lane & 15)) * 72 + ko);
      bf16x8 b0 = *(const bf16x8*)(Bs + (nw * 32 + (lane & 15)) * 72 + ko);
      bf16x8 b1 = *(const bf16x8*)(Bs + (nw * 32 + 16 + (lane & 15)) * 72 + ko);
      acc[0][0] = mfma16(a0, b0, acc[0][0]);
      acc[0][1] = mfma16(a0, b1, acc[0][1]);
      acc[1][0] = mfma16(a1, b0, acc[1][0]);
      acc[1][1] = mfma16(a1, b1, acc[1][1]);
    }
    __syncthreads();
  }
  int quad = lane >> 4, cl = lane & 15;
#pragma unroll
  for (int mt = 0; mt < 2; mt++) {
#pragma unroll
    for (int nt = 0; nt < 2; nt++) {
      int col = bn * 64 + nw * 32 + nt * 16 + cl;
      float bo = ldf(b_out, col, is32);
#pragma unroll
      for (int i = 0; i < 4; i++) {
        int r = row0 + mw * 32 + mt * 16 + quad * 4 + i;
        int l = r & 511;
        float v = acc[mt][nt][i] + bo;
        if (mask[l] == 0) v = 0.f;
        if (is32) ((float*)outp)[(size_t)r * 256 + col] = v;
        else ((bf16_t*)outp)[(size_t)r * 256 + col] = (bf16_t)v;
      }
    }
  }
}

extern "C" void kernel_launch(void* const* d_in, const int* in_sizes, int n_in,
                              void* d_out, int out_size, void* d_ws, size_t ws_size,
                              hipStream_t stream) {
  const void* msa      = d_in[0];
  const void* pair     = d_in[1];
  const void* ln_msa_g = d_in[2];
  const void* ln_msa_b = d_in[3];
  const void* ln_pair_g= d_in[4];
  const void* ln_pair_b= d_in[5];
  const void* w_q      = d_in[6];
  const void* w_k      = d_in[7];
  const void* w_v      = d_in[8];
  const void* w_b      = d_in[9];
  const void* w_g      = d_in[10];
  const void* b_g      = d_in[11];
  const void* w_out    = d_in[12];
  const void* b_out    = d_in[13];
  const int*  mask     = (const int*)d_in[14];

  char* ws = (char*)d_ws;
  bf16_t* qkg   = (bf16_t*)(ws + OFF_QKG);
  float*  logit = (float*)(ws + OFF_LOG);
  float*  biasb = (float*)(ws + OFF_BIAS);
  bf16_t* pbuf  = (bf16_t*)(ws + OFF_P);
  bf16_t* wtc   = (bf16_t*)(ws + OFF_WT);
  bf16_t* wto   = (bf16_t*)(ws + OFF_WTO);
  int*    flag  = (int*)(ws + OFF_FLAG);
  bf16_t* vt    = (bf16_t*)d_out;  // dead before k_out writes final output

  k_detect<<<1, 256, 0, stream>>>((const unsigned short*)msa, flag);
  k_transpose<<<1280, 256, 0, stream>>>(w_q, w_k, w_v, w_g, w_out, flag, wtc, wto);
  k_pair_bias<<<65536, 256, 0, stream>>>(pair, ln_pair_g, ln_pair_b, w_b, flag, biasb);
  k_lnproj<<<32768, 256, 0, stream>>>(msa, ln_msa_g, ln_msa_b, wtc, b_g, mask, flag, qkg, vt);
  k_logits<<<512, 256, 0, stream>>>(qkg, logit);
  k_softmax<<<4096, 256, 0, stream>>>(logit, biasb, mask, pbuf);
  k_av<<<16384, 256, 0, stream>>>(pbuf, vt, qkg);
  k_out<<<8192, 256, 0, stream>>>(qkg, wto, b_out, mask, flag, d_out);
}

// Round 4
// 1509.413 us; speedup vs baseline: 1.0925x; 1.0925x over previous
//
#include <hip/hip_runtime.h>
#include <hip/hip_bf16.h>
#include <math.h>

typedef __bf16 bf16_t;
typedef float f32x4 __attribute__((ext_vector_type(4)));
typedef __bf16 bf16x8 __attribute__((ext_vector_type(8)));
typedef __bf16 bf16x4 __attribute__((ext_vector_type(4)));
typedef int i32x4 __attribute__((ext_vector_type(4)));

#define SCALING 0.17677669529663687f
#define LNEPS 1e-5f

// ws layout (bytes); total = 224,002,176 (vt lives in d_out)
#define OFF_QKG   0u            // bf16 [131072][768]: q | k | gate; q-region reused for gated AV out
#define OFF_LOG   201326592u    // f32  [8][512][512]: attn logits
#define OFF_BIAS  209715200u    // f32  [8][512][512]: pair bias
#define OFF_P     218103808u    // bf16 [8][512][512]: softmax probs
#define OFF_WT    222298112u    // bf16 [1024][256]  : [wq|wk|wv|wg]^T
#define OFF_WTO   222822400u    // bf16 [256][256]   : w_out^T
#define OFF_FLAG  222953472u    // int: 1 if inputs are fp32, 0 if bf16
#define OFF_STATS 222953600u    // float2 [131072]   : per-row (mu, rs) of msa LN

static __device__ __forceinline__ f32x4 mfma16(bf16x8 a, bf16x8 b, f32x4 c) {
  return __builtin_amdgcn_mfma_f32_16x16x32_bf16(a, b, c, 0, 0, 0);
}

static __device__ __forceinline__ float ldf(const void* p, int i, int is32) {
  return is32 ? ((const float*)p)[i] : (float)((const bf16_t*)p)[i];
}
static __device__ __forceinline__ float scrubf(float x) {
  if (x != x) return 0.f;
  return fminf(fmaxf(x, -3.3e38f), 3.3e38f);
}

// ---------------- K-1: detect input dtype ----------------
__global__ __launch_bounds__(256) void k_detect(const unsigned short* raw, int* flag) {
  __shared__ int s;
  int t = threadIdx.x;
  if (t == 0) s = 0;
  __syncthreads();
  int local = 0;
  for (int i = 0; i < 16; i++) {
    unsigned short u = raw[t * 16 + i];
    int e = (u >> 7) & 0xFF;
    if (e >= 170) local = 1;   // |x| >= 2^43 as bf16: impossible for N(0,1) bf16 data
  }
  if (local) s = 1;
  __syncthreads();
  if (t == 0) *flag = s;
}

// ---------------- K0: transpose weights (any dtype -> bf16) ----------------
__global__ __launch_bounds__(256) void k_transpose(
    const void* wq, const void* wk, const void* wv, const void* wg,
    const void* wout, const int* flag, bf16_t* wt_cat, bf16_t* wt_out) {
  int is32 = *flag;
  int idx = blockIdx.x * 256 + threadIdx.x;
  if (idx < 1024 * 256) {
    int c = idx >> 8, k = idx & 255;
    const void* src = (c < 256) ? wq : (c < 512) ? wk : (c < 768) ? wv : wg;
    wt_cat[c * 256 + k] = (bf16_t)ldf(src, k * 256 + (c & 255), is32);
  } else {
    int i2 = idx - 1024 * 256;  // < 65536
    int c = i2 >> 8, k = i2 & 255;
    wt_out[c * 256 + k] = (bf16_t)ldf(wout, k * 256 + c, is32);
  }
}

// ---------------- K1: per-row LN stats of msa -> (mu, rs) ----------------
__global__ __launch_bounds__(256) void k_stats(const void* msa, const int* flag, float2* stats) {
  int is32 = *flag;
  int t = threadIdx.x, lane = t & 63, w = t >> 6;
  int row0 = blockIdx.x * 64 + w * 16;
  for (int rr = 0; rr < 16; rr++) {
    int r = row0 + rr;
    float x0, x1, x2, x3;
    if (is32) {
      f32x4 v = *(const f32x4*)((const float*)msa + (size_t)r * 256 + lane * 4);
      x0 = scrubf(v[0]); x1 = scrubf(v[1]); x2 = scrubf(v[2]); x3 = scrubf(v[3]);
    } else {
      bf16x4 v = *(const bf16x4*)((const bf16_t*)msa + (size_t)r * 256 + lane * 4);
      x0 = scrubf((float)v[0]); x1 = scrubf((float)v[1]);
      x2 = scrubf((float)v[2]); x3 = scrubf((float)v[3]);
    }
    float s = x0 + x1 + x2 + x3;
    float sq = x0 * x0 + x1 * x1 + x2 * x2 + x3 * x3;
#pragma unroll
    for (int o = 32; o >= 1; o >>= 1) {
      s += __shfl_xor(s, o, 64);
      sq += __shfl_xor(sq, o, 64);
    }
    float mu = s * (1.f / 256.f);
    float var = sq * (1.f / 256.f) - mu * mu;
    float rs = rsqrtf(fmaxf(var, 0.f) + LNEPS);
    if (lane == 0) stats[r] = make_float2(mu, rs);
  }
}

// ---------------- K2: pair LN + @ w_b -> bias[h][q][k] (f32) ----------------
__global__ __launch_bounds__(256) void k_pair_bias(
    const void* pair, const void* g, const void* b,
    const void* wb, const int* flag, float* bias_ws) {
  int is32 = *flag;
  int lane = threadIdx.x & 63;
  int w = threadIdx.x >> 6;
  int row = blockIdx.x * 4 + w;  // (qp*512 + kp), 0..262143
  float x0 = scrubf(ldf(pair, row * 128 + 2 * lane, is32));
  float x1 = scrubf(ldf(pair, row * 128 + 2 * lane + 1, is32));
  float s = x0 + x1, sq = x0 * x0 + x1 * x1;
#pragma unroll
  for (int o = 32; o >= 1; o >>= 1) {
    s += __shfl_xor(s, o, 64);
    sq += __shfl_xor(sq, o, 64);
  }
  float mu = s * (1.f / 128.f);
  float var = sq * (1.f / 128.f) - mu * mu;
  float rs = rsqrtf(fmaxf(var, 0.f) + LNEPS);
  float xn0 = (x0 - mu) * rs * ldf(g, 2 * lane, is32) + ldf(b, 2 * lane, is32);
  float xn1 = (x1 - mu) * rs * ldf(g, 2 * lane + 1, is32) + ldf(b, 2 * lane + 1, is32);
  float ph[8];
#pragma unroll
  for (int hh = 0; hh < 8; hh++)
    ph[hh] = xn0 * ldf(wb, (2 * lane) * 8 + hh, is32) + xn1 * ldf(wb, (2 * lane + 1) * 8 + hh, is32);
#pragma unroll
  for (int o = 32; o >= 1; o >>= 1) {
#pragma unroll
    for (int hh = 0; hh < 8; hh++) ph[hh] += __shfl_xor(ph[hh], o, 64);
  }
  if (lane == 0) {
    int qp = row >> 9, kp = row & 511;
    float* bp = bias_ws + (size_t)qp * 512 + kp;
#pragma unroll
    for (int hh = 0; hh < 8; hh++) bp[(size_t)hh * 262144] = ph[hh];
  }
}

// ---------------- K3: QKVG projection GEMM (LN applied on stage) ----------------
// grid 8192: bm(1024) x bn(8, innermost for L2/L3 A reuse); block 256; tile 128x128, K=256
__global__ __launch_bounds__(256) void k_proj(
    const void* msa, const void* lng, const void* lnb,
    const bf16_t* wt_cat, const void* bg, const int* mask, const int* flag,
    const float2* stats, bf16_t* qkg, bf16_t* vt) {
  __shared__ bf16_t As[128 * 72];
  __shared__ bf16_t Bs[128 * 72];
  int is32 = *flag;
  int t = threadIdx.x, lane = t & 63, w = t >> 6;
  int bm = blockIdx.x >> 3, bn = blockIdx.x & 7;
  int row0 = bm * 128, col0 = bn * 128;
  int mw = w & 1, nw = w >> 1;

  f32x4 z = {0.f, 0.f, 0.f, 0.f};
  f32x4 acc[4][4] = {{z, z, z, z}, {z, z, z, z}, {z, z, z, z}, {z, z, z, z}};

  // hoist per-thread row stats (rows fixed across k-iters)
  float2 st32[8];  // fp32 path: r = (t>>4) + i*16
  float2 st16[4];  // bf16 path: r = (t>>3) + i*32
  if (is32) {
#pragma unroll
    for (int i = 0; i < 8; i++) st32[i] = stats[row0 + (t >> 4) + i * 16];
  } else {
#pragma unroll
    for (int i = 0; i < 4; i++) st16[i] = stats[row0 + (t >> 3) + i * 32];
  }

  for (int kt = 0; kt < 4; kt++) {
    // ---- stage A (normalize fp32/bf16 -> bf16) ----
    if (is32) {
      int c4 = t & 15;
      float gv[4], bv[4];
#pragma unroll
      for (int e = 0; e < 4; e++) {
        gv[e] = ((const float*)lng)[kt * 64 + c4 * 4 + e];
        bv[e] = ((const float*)lnb)[kt * 64 + c4 * 4 + e];
      }
#pragma unroll
      for (int i = 0; i < 8; i++) {
        int r = (t >> 4) + i * 16;
        f32x4 x = *(const f32x4*)((const float*)msa + (size_t)(row0 + r) * 256 + kt * 64 + c4 * 4);
        float mu = st32[i].x, rs = st32[i].y;
        bf16x4 y;
#pragma unroll
        for (int e = 0; e < 4; e++) y[e] = (bf16_t)((scrubf(x[e]) - mu) * rs * gv[e] + bv[e]);
        *(bf16x4*)(As + r * 72 + c4 * 4) = y;
      }
    } else {
      int c8 = t & 7;
      float gv[8], bv[8];
#pragma unroll
      for (int e = 0; e < 8; e++) {
        gv[e] = (float)((const bf16_t*)lng)[kt * 64 + c8 * 8 + e];
        bv[e] = (float)((const bf16_t*)lnb)[kt * 64 + c8 * 8 + e];
      }
#pragma unroll
      for (int i = 0; i < 4; i++) {
        int r = (t >> 3) + i * 32;
        i32x4 raw = *(const i32x4*)((const bf16_t*)msa + (size_t)(row0 + r) * 256 + kt * 64 + c8 * 8);
        const bf16_t* sp = (const bf16_t*)&raw;
        float mu = st16[i].x, rs = st16[i].y;
        bf16x8 y;
#pragma unroll
        for (int e = 0; e < 8; e++) y[e] = (bf16_t)((scrubf((float)sp[e]) - mu) * rs * gv[e] + bv[e]);
        *(bf16x8*)(As + r * 72 + c8 * 8) = y;
      }
    }
    // ---- stage B ----
#pragma unroll
    for (int i = 0; i < 4; i++) {
      int flat = t + i * 256;  // 0..1023
      int br = flat >> 3, c8 = flat & 7;
      *(i32x4*)(Bs + br * 72 + c8 * 8) =
          *(const i32x4*)(wt_cat + (size_t)(col0 + br) * 256 + kt * 64 + c8 * 8);
    }
    __syncthreads();
    // ---- MFMA ----
#pragma unroll
    for (int kk = 0; kk < 64; kk += 32) {
      int ko = kk + (lane >> 4) * 8;
      bf16x8 a[4], b[4];
#pragma unroll
      for (int m = 0; m < 4; m++)
        a[m] = *(const bf16x8*)(As + (mw * 64 + m * 16 + (lane & 15)) * 72 + ko);
#pragma unroll
      for (int n = 0; n < 4; n++)
        b[n] = *(const bf16x8*)(Bs + (nw * 64 + n * 16 + (lane & 15)) * 72 + ko);
#pragma unroll
      for (int m = 0; m < 4; m++)
#pragma unroll
        for (int n = 0; n < 4; n++) acc[m][n] = mfma16(a[m], b[n], acc[m][n]);
    }
    __syncthreads();
  }

  // ---- epilogue ----
  int quad = lane >> 4, cl = lane & 15;
  int region = bn >> 1;  // 0:q 1:k 2:v 3:gate (uniform per block)
#pragma unroll
  for (int m = 0; m < 4; m++) {
#pragma unroll
    for (int n = 0; n < 4; n++) {
      int col = col0 + nw * 64 + n * 16 + cl;
#pragma unroll
      for (int i = 0; i < 4; i++) {
        int r = row0 + mw * 64 + m * 16 + quad * 4 + i;
        int l = r & 511;
        bool pad = (mask[l] == 0);
        float v = acc[m][n][i];
        if (region == 0) {
          qkg[(size_t)r * 768 + col] = (bf16_t)(pad ? 0.f : v);
        } else if (region == 1) {
          qkg[(size_t)r * 768 + col] = (bf16_t)(pad ? 0.f : v * SCALING);
        } else if (region == 2) {
          int hd = col & 255;
          vt[((size_t)((r >> 9) * 8 + (hd >> 5)) * 32 + (hd & 31)) * 512 + l] =
              (bf16_t)(pad ? 0.f : v);
        } else {
          int gcol = col & 255;
          float x = v + ldf(bg, gcol, is32);
          qkg[(size_t)r * 768 + 512 + gcol] = (bf16_t)(1.f / (1.f + __expf(-x)));
        }
      }
    }
  }
}

// ---------------- K4: logits[h][q][k] = sum_{n,d} q*k ----------------
__global__ __launch_bounds__(256) void k_logits(const bf16_t* qkg, float* logit_ws) {
  __shared__ bf16_t As[64 * 136];
  __shared__ bf16_t Bs[64 * 136];
  int t = threadIdx.x, lane = t & 63, w = t >> 6;
  int ktile = blockIdx.x & 7, qtile = (blockIdx.x >> 3) & 7, h = blockIdx.x >> 6;
  int mw = w & 1, nw = w >> 1;
  f32x4 z = {0.f, 0.f, 0.f, 0.f};
  f32x4 acc[2][2] = {{z, z}, {z, z}};
  for (int s = 0; s < 64; s++) {
    int kk0 = s * 128;
#pragma unroll
    for (int i = 0; i < 4; i++) {
      int flat = t + i * 256;  // 1024 chunks
      int r = flat >> 4, c8 = flat & 15;
      int kk = kk0 + c8 * 8;
      int n = kk >> 5, d = kk & 31;
      i32x4 va = *(const i32x4*)(qkg + ((size_t)(n * 512 + qtile * 64 + r)) * 768 + h * 32 + d);
      *(i32x4*)(As + r * 136 + c8 * 8) = va;
      i32x4 vb = *(const i32x4*)(qkg + ((size_t)(n * 512 + ktile * 64 + r)) * 768 + 256 + h * 32 + d);
      *(i32x4*)(Bs + r * 136 + c8 * 8) = vb;
    }
    __syncthreads();
#pragma unroll
    for (int kk = 0; kk < 128; kk += 32) {
      int ko = kk + (lane >> 4) * 8;
      bf16x8 a0 = *(const bf16x8*)(As + (mw * 32 + (lane & 15)) * 136 + ko);
      bf16x8 a1 = *(const bf16x8*)(As + (mw * 32 + 16 + (lane & 15)) * 136 + ko);
      bf16x8 b0 = *(const bf16x8*)(Bs + (nw * 32 + (lane & 15)) * 136 + ko);
      bf16x8 b1 = *(const bf16x8*)(Bs + (nw * 32 + 16 + (lane & 15)) * 136 + ko);
      acc[0][0] = mfma16(a0, b0, acc[0][0]);
      acc[0][1] = mfma16(a0, b1, acc[0][1]);
      acc[1][0] = mfma16(a1, b0, acc[1][0]);
      acc[1][1] = mfma16(a1, b1, acc[1][1]);
    }
    __syncthreads();
  }
  int quad = lane >> 4, cl = lane & 15;
#pragma unroll
  for (int mt = 0; mt < 2; mt++) {
#pragma unroll
    for (int nt = 0; nt < 2; nt++) {
      int kp = ktile * 64 + nw * 32 + nt * 16 + cl;
#pragma unroll
      for (int i = 0; i < 4; i++) {
        int q = qtile * 64 + mw * 32 + mt * 16 + quad * 4 + i;
        logit_ws[((size_t)(h * 512 + q)) * 512 + kp] = acc[mt][nt][i];
      }
    }
  }
}

// ---------------- K5: softmax over k with bias + 2D mask ----------------
__global__ __launch_bounds__(256) void k_softmax(
    const float* logit_ws, const float* bias_ws, const int* mask, bf16_t* p_ws) {
  __shared__ float red[8];
  int t = threadIdx.x;
  int hq = blockIdx.x;  // h*512 + q
  int q = hq & 511;
  bool padq = (mask[q] == 0);
  const float* lg = logit_ws + (size_t)hq * 512;
  const float* bi = bias_ws + (size_t)(hq >> 9) * 262144 + (size_t)q * 512;
  int k0 = t * 2;
  float v0 = lg[k0] + bi[k0];
  float v1 = lg[k0 + 1] + bi[k0 + 1];
  if (padq || mask[k0] == 0) v0 = -1e9f;
  if (padq || mask[k0 + 1] == 0) v1 = -1e9f;
  float m = fmaxf(v0, v1);
#pragma unroll
  for (int o = 32; o >= 1; o >>= 1) m = fmaxf(m, __shfl_xor(m, o, 64));
  if ((t & 63) == 0) red[t >> 6] = m;
  __syncthreads();
  m = fmaxf(fmaxf(red[0], red[1]), fmaxf(red[2], red[3]));
  float e0 = __expf(v0 - m), e1 = __expf(v1 - m);
  float s = e0 + e1;
#pragma unroll
  for (int o = 32; o >= 1; o >>= 1) s += __shfl_xor(s, o, 64);
  if ((t & 63) == 0) red[4 + (t >> 6)] = s;
  __syncthreads();
  s = red[4] + red[5] + red[6] + red[7];
  float inv = 1.f / s;
  p_ws[(size_t)hq * 512 + k0] = (bf16_t)(e0 * inv);
  p_ws[(size_t)hq * 512 + k0 + 1] = (bf16_t)(e1 * inv);
}

// ---------------- K6: O = P @ V, * gate -> q-region of qkg ----------------
__global__ __launch_bounds__(256) void k_av(
    const bf16_t* p_ws, const bf16_t* vt, bf16_t* qkg) {
  __shared__ bf16_t Ps[64 * 136];
  __shared__ bf16_t Vs[32 * 136];
  int t = threadIdx.x, lane = t & 63, w = t >> 6;
  int n = blockIdx.x & 255;
  int rest = blockIdx.x >> 8;
  int qt = rest & 7, h = rest >> 3;
  f32x4 z = {0.f, 0.f, 0.f, 0.f};
  f32x4 acc[2] = {z, z};
  for (int s = 0; s < 4; s++) {
    int k0 = s * 128;
#pragma unroll
    for (int i = 0; i < 4; i++) {
      int flat = t + i * 256;
      int r = flat >> 4, c8 = flat & 15;
      *(i32x4*)(Ps + r * 136 + c8 * 8) =
          *(const i32x4*)(p_ws + ((size_t)(h * 512 + qt * 64 + r)) * 512 + k0 + c8 * 8);
    }
#pragma unroll
    for (int i = 0; i < 2; i++) {
      int flat = t + i * 256;
      int r = flat >> 4, c8 = flat & 15;  // r = d
      *(i32x4*)(Vs + r * 136 + c8 * 8) =
          *(const i32x4*)(vt + ((size_t)((n * 8 + h) * 32 + r)) * 512 + k0 + c8 * 8);
    }
    __syncthreads();
#pragma unroll
    for (int kk = 0; kk < 128; kk += 32) {
      int ko = kk + (lane >> 4) * 8;
      bf16x8 a = *(const bf16x8*)(Ps + (w * 16 + (lane & 15)) * 136 + ko);
      bf16x8 b0 = *(const bf16x8*)(Vs + ((lane & 15)) * 136 + ko);
      bf16x8 b1 = *(const bf16x8*)(Vs + (16 + (lane & 15)) * 136 + ko);
      acc[0] = mfma16(a, b0, acc[0]);
      acc[1] = mfma16(a, b1, acc[1]);
    }
    __syncthreads();
  }
  int quad = lane >> 4, cl = lane & 15;
#pragma unroll
  for (int nt = 0; nt < 2; nt++) {
#pragma unroll
    for (int i = 0; i < 4; i++) {
      int q = qt * 64 + w * 16 + quad * 4 + i;
      int d = nt * 16 + cl;
      size_t base = ((size_t)(n * 512 + q)) * 768;
      float gate = (float)qkg[base + 512 + h * 32 + d];
      qkg[base + h * 32 + d] = (bf16_t)(acc[nt][i] * gate);
    }
  }
}

// ---------------- K7: out = gated @ w_out + b_out, pad-zeroed ----------------
__global__ __launch_bounds__(256) void k_out(
    const bf16_t* qkg, const bf16_t* wt_out, const void* b_out,
    const int* mask, const int* flag, void* outp) {
  __shared__ bf16_t As[64 * 72];
  __shared__ bf16_t Bs[64 * 72];
  int is32 = *flag;
  int t = threadIdx.x, lane = t & 63, w = t >> 6;
  int bm = blockIdx.x >> 2, bn = blockIdx.x & 3;
  int row0 = bm * 64;
  int mw = w & 1, nw = w >> 1;
  f32x4 z = {0.f, 0.f, 0.f, 0.f};
  f32x4 acc[2][2] = {{z, z}, {z, z}};
  for (int kt = 0; kt < 4; kt++) {
#pragma unroll
    for (int i = 0; i < 2; i++) {
      int flat = t + i * 256;
      int r = flat >> 3, c8 = flat & 7;
      *(i32x4*)(As + r * 72 + c8 * 8) =
          *(const i32x4*)(qkg + (size_t)(row0 + r) * 768 + kt * 64 + c8 * 8);
      *(i32x4*)(Bs + r * 72 + c8 * 8) =
          *(const i32x4*)(wt_out + (size_t)(bn * 64 + r) * 256 + kt * 64 + c8 * 8);
    }
    __syncthreads();
#pragma unroll
    for (int kk = 0; kk < 64; kk += 32) {
      int ko = kk + (lane >> 4) * 8;
      bf16x8 a0 = *(const bf16x8*)(As + (mw * 32 + (lane & 15)) * 72 + ko);
      bf16x8 a1 = *(const bf16x8*)(As + (mw * 32 + 16 + (lane & 15)) * 72 + ko);
      bf16x8 b0 = *(const bf16x8*)(Bs + (nw * 32 + (lane & 15)) * 72 + ko);
      bf16x8 b1 = *(const bf16x8*)(Bs + (nw * 32 + 16 + (lane & 15)) * 72 + ko);
      acc[0][0] = mfma16(a0, b0, acc[0][0]);
      acc[0][1] = mfma16(a0, b1, acc[0][1]);
      acc[1][0] = mfma16(a1, b0, acc[1][0]);
      acc[1][1] = mfma16(a1, b1, acc[1][1]);
    }
    __syncthreads();
  }
  int quad = lane >> 4, cl = lane & 15;
#pragma unroll
  for (int mt = 0; mt < 2; mt++) {
#pragma unroll
    for (int nt = 0; nt < 2; nt++) {
      int col = bn * 64 + nw * 32 + nt * 16 + cl;
      float bo = ldf(b_out, col, is32);
#pragma unroll
      for (int i = 0; i < 4; i++) {
        int r = row0 + mw * 32 + mt * 16 + quad * 4 + i;
        int l = r & 511;
        float v = acc[mt][nt][i] + bo;
        if (mask[l] == 0) v = 0.f;
        if (is32) ((float*)outp)[(size_t)r * 256 + col] = v;
        else ((bf16_t*)outp)[(size_t)r * 256 + col] = (bf16_t)v;
      }
    }
  }
}

extern "C" void kernel_launch(void* const* d_in, const int* in_sizes, int n_in,
                              void* d_out, int out_size, void* d_ws, size_t ws_size,
                              hipStream_t stream) {
  const void* msa      = d_in[0];
  const void* pair     = d_in[1];
  const void* ln_msa_g = d_in[2];
  const void* ln_msa_b = d_in[3];
  const void* ln_pair_g= d_in[4];
  const void* ln_pair_b= d_in[5];
  const void* w_q      = d_in[6];
  const void* w_k      = d_in[7];
  const void* w_v      = d_in[8];
  const void* w_b      = d_in[9];
  const void* w_g      = d_in[10];
  const void* b_g      = d_in[11];
  const void* w_out    = d_in[12];
  const void* b_out    = d_in[13];
  const int*  mask     = (const int*)d_in[14];

  char* ws = (char*)d_ws;
  bf16_t* qkg   = (bf16_t*)(ws + OFF_QKG);
  float*  logit = (float*)(ws + OFF_LOG);
  float*  biasb = (float*)(ws + OFF_BIAS);
  bf16_t* pbuf  = (bf16_t*)(ws + OFF_P);
  bf16_t* wtc   = (bf16_t*)(ws + OFF_WT);
  bf16_t* wto   = (bf16_t*)(ws + OFF_WTO);
  int*    flag  = (int*)(ws + OFF_FLAG);
  float2* stats = (float2*)(ws + OFF_STATS);
  bf16_t* vt    = (bf16_t*)d_out;  // dead before k_out writes final output

  k_detect<<<1, 256, 0, stream>>>((const unsigned short*)msa, flag);
  k_transpose<<<1280, 256, 0, stream>>>(w_q, w_k, w_v, w_g, w_out, flag, wtc, wto);
  k_stats<<<2048, 256, 0, stream>>>(msa, flag, stats);
  k_pair_bias<<<65536, 256, 0, stream>>>(pair, ln_pair_g, ln_pair_b, w_b, flag, biasb);
  k_proj<<<8192, 256, 0, stream>>>(msa, ln_msa_g, ln_msa_b, wtc, b_g, mask, flag, stats, qkg, vt);
  k_logits<<<512, 256, 0, stream>>>(qkg, logit);
  k_softmax<<<4096, 256, 0, stream>>>(logit, biasb, mask, pbuf);
  k_av<<<16384, 256, 0, stream>>>(pbuf, vt, qkg);
  k_out<<<8192, 256, 0, stream>>>(qkg, wto, b_out, mask, flag, d_out);
}

// Round 5
// 1082.264 us; speedup vs baseline: 1.5236x; 1.3947x over previous
//
#include <hip/hip_runtime.h>
#include <hip/hip_bf16.h>
#include <math.h>

typedef __bf16 bf16_t;
typedef float f32x4 __attribute__((ext_vector_type(4)));
typedef __bf16 bf16x8 __attribute__((ext_vector_type(8)));
typedef __bf16 bf16x4 __attribute__((ext_vector_type(4)));
typedef int i32x4 __attribute__((ext_vector_type(4)));

#define SCALING 0.17677669529663687f
#define LNEPS 1e-5f

// ws layout (bytes); total = 224,002,176 (vt lives in d_out)
#define OFF_QKG   0u            // bf16 [131072][768]: q | k | gate; q-region reused for gated AV out
#define OFF_LOG   201326592u    // f32  [8][512][512]: attn logits
#define OFF_BIAS  209715200u    // f32  [8][512][512]: pair bias
#define OFF_P     218103808u    // bf16 [8][512][512]: softmax probs
#define OFF_WT    222298112u    // bf16 [1024][256]  : [wq|wk|wv|wg]^T
#define OFF_WTO   222822400u    // bf16 [256][256]   : w_out^T
#define OFF_FLAG  222953472u    // int: 1 if inputs are fp32, 0 if bf16
#define OFF_STATS 222953600u    // float2 [131072]   : per-row (mu, rs) of msa LN

static __device__ __forceinline__ f32x4 mfma16(bf16x8 a, bf16x8 b, f32x4 c) {
  return __builtin_amdgcn_mfma_f32_16x16x32_bf16(a, b, c, 0, 0, 0);
}

static __device__ __forceinline__ float ldf(const void* p, int i, int is32) {
  return is32 ? ((const float*)p)[i] : (float)((const bf16_t*)p)[i];
}
static __device__ __forceinline__ float scrubf(float x) {
  if (x != x) return 0.f;
  return fminf(fmaxf(x, -3.3e38f), 3.3e38f);
}

// ---------------- K-1: detect input dtype ----------------
__global__ __launch_bounds__(256) void k_detect(const unsigned short* raw, int* flag) {
  __shared__ int s;
  int t = threadIdx.x;
  if (t == 0) s = 0;
  __syncthreads();
  int local = 0;
  for (int i = 0; i < 16; i++) {
    unsigned short u = raw[t * 16 + i];
    int e = (u >> 7) & 0xFF;
    if (e >= 170) local = 1;   // |x| >= 2^43 as bf16: impossible for N(0,1) bf16 data
  }
  if (local) s = 1;
  __syncthreads();
  if (t == 0) *flag = s;
}

// ---------------- K0: transpose weights (any dtype -> bf16) ----------------
__global__ __launch_bounds__(256) void k_transpose(
    const void* wq, const void* wk, const void* wv, const void* wg,
    const void* wout, const int* flag, bf16_t* wt_cat, bf16_t* wt_out) {
  int is32 = *flag;
  int idx = blockIdx.x * 256 + threadIdx.x;
  if (idx < 1024 * 256) {
    int c = idx >> 8, k = idx & 255;
    const void* src = (c < 256) ? wq : (c < 512) ? wk : (c < 768) ? wv : wg;
    wt_cat[c * 256 + k] = (bf16_t)ldf(src, k * 256 + (c & 255), is32);
  } else {
    int i2 = idx - 1024 * 256;  // < 65536
    int c = i2 >> 8, k = i2 & 255;
    wt_out[c * 256 + k] = (bf16_t)ldf(wout, k * 256 + c, is32);
  }
}

// ---------------- K1: per-row LN stats of msa -> (mu, rs) ----------------
__global__ __launch_bounds__(256) void k_stats(const void* msa, const int* flag, float2* stats) {
  int is32 = *flag;
  int t = threadIdx.x, lane = t & 63, w = t >> 6;
  int row0 = blockIdx.x * 64 + w * 16;
  for (int rr = 0; rr < 16; rr++) {
    int r = row0 + rr;
    float x0, x1, x2, x3;
    if (is32) {
      f32x4 v = *(const f32x4*)((const float*)msa + (size_t)r * 256 + lane * 4);
      x0 = scrubf(v[0]); x1 = scrubf(v[1]); x2 = scrubf(v[2]); x3 = scrubf(v[3]);
    } else {
      bf16x4 v = *(const bf16x4*)((const bf16_t*)msa + (size_t)r * 256 + lane * 4);
      x0 = scrubf((float)v[0]); x1 = scrubf((float)v[1]);
      x2 = scrubf((float)v[2]); x3 = scrubf((float)v[3]);
    }
    float s = x0 + x1 + x2 + x3;
    float sq = x0 * x0 + x1 * x1 + x2 * x2 + x3 * x3;
#pragma unroll
    for (int o = 32; o >= 1; o >>= 1) {
      s += __shfl_xor(s, o, 64);
      sq += __shfl_xor(sq, o, 64);
    }
    float mu = s * (1.f / 256.f);
    float var = sq * (1.f / 256.f) - mu * mu;
    float rs = rsqrtf(fmaxf(var, 0.f) + LNEPS);
    if (lane == 0) stats[r] = make_float2(mu, rs);
  }
}

// ---------------- K2: pair LN + @ w_b -> bias[h][q][k] (f32) ----------------
// grid 4096, 64 rows/block. 8 lanes per row, 16 elems/lane, 3-stage reductions.
__global__ __launch_bounds__(256) void k_pair_bias(
    const void* pair, const void* g, const void* b,
    const void* wb, const int* flag, float* bias_ws) {
  __shared__ float wbs[128 * 8];  // wb[c][h]
  __shared__ float gs[128], bs[128];
  int is32 = *flag;
  int t = threadIdx.x;
  if (t < 128) { gs[t] = ldf(g, t, is32); bs[t] = ldf(b, t, is32); }
  for (int i = t; i < 1024; i += 256) wbs[i] = ldf(wb, i, is32);
  __syncthreads();
  int lane = t & 63, w = t >> 6;
  int j = lane & 7;        // element-group within row (16 elems each)
  int rowg = lane >> 3;    // row within pass (0..7)
  float gr[16], br[16];
#pragma unroll
  for (int e = 0; e < 16; e++) { gr[e] = gs[j * 16 + e]; br[e] = bs[j * 16 + e]; }
  int row0 = blockIdx.x * 64 + w * 16;
#pragma unroll
  for (int pass = 0; pass < 2; pass++) {
    int row = row0 + pass * 8 + rowg;
    float x[16];
    if (is32) {
#pragma unroll
      for (int i = 0; i < 4; i++) {
        f32x4 v = *(const f32x4*)((const float*)pair + (size_t)row * 128 + j * 16 + i * 4);
#pragma unroll
        for (int e = 0; e < 4; e++) x[i * 4 + e] = scrubf(v[e]);
      }
    } else {
#pragma unroll
      for (int i = 0; i < 2; i++) {
        i32x4 raw = *(const i32x4*)((const bf16_t*)pair + (size_t)row * 128 + j * 16 + i * 8);
        const bf16_t* sp = (const bf16_t*)&raw;
#pragma unroll
        for (int e = 0; e < 8; e++) x[i * 8 + e] = scrubf((float)sp[e]);
      }
    }
    float s = 0.f, sq = 0.f;
#pragma unroll
    for (int e = 0; e < 16; e++) { s += x[e]; sq += x[e] * x[e]; }
#pragma unroll
    for (int o = 1; o <= 4; o <<= 1) {
      s += __shfl_xor(s, o, 64);
      sq += __shfl_xor(sq, o, 64);
    }
    float mu = s * (1.f / 128.f);
    float var = sq * (1.f / 128.f) - mu * mu;
    float rs = rsqrtf(fmaxf(var, 0.f) + LNEPS);
    float ph[8] = {0.f, 0.f, 0.f, 0.f, 0.f, 0.f, 0.f, 0.f};
#pragma unroll
    for (int e = 0; e < 16; e++) {
      float xn = (x[e] - mu) * rs * gr[e] + br[e];
      const float* wp = wbs + (j * 16 + e) * 8;
      f32x4 w0 = *(const f32x4*)wp;
      f32x4 w1 = *(const f32x4*)(wp + 4);
#pragma unroll
      for (int hh = 0; hh < 4; hh++) { ph[hh] += xn * w0[hh]; ph[4 + hh] += xn * w1[hh]; }
    }
#pragma unroll
    for (int o = 1; o <= 4; o <<= 1) {
#pragma unroll
      for (int hh = 0; hh < 8; hh++) ph[hh] += __shfl_xor(ph[hh], o, 64);
    }
    if (j == 0) {
      int qp = row >> 9, kp = row & 511;
      float* bp = bias_ws + (size_t)qp * 512 + kp;
#pragma unroll
      for (int hh = 0; hh < 8; hh++) bp[(size_t)hh * 262144] = ph[hh];
    }
  }
}

// ---------------- K3: QKVG projection GEMM (LN applied on stage) ----------------
// grid 8192: bm(1024) x bn(8, innermost for L2/L3 A reuse); block 256; tile 128x128, K=256
__global__ __launch_bounds__(256) void k_proj(
    const void* msa, const void* lng, const void* lnb,
    const bf16_t* wt_cat, const void* bg, const int* mask, const int* flag,
    const float2* stats, bf16_t* qkg, bf16_t* vt) {
  __shared__ bf16_t As[128 * 72];
  __shared__ bf16_t Bs[128 * 72];
  int is32 = *flag;
  int t = threadIdx.x, lane = t & 63, w = t >> 6;
  int bm = blockIdx.x >> 3, bn = blockIdx.x & 7;
  int row0 = bm * 128, col0 = bn * 128;
  int mw = w & 1, nw = w >> 1;

  f32x4 z = {0.f, 0.f, 0.f, 0.f};
  f32x4 acc[4][4] = {{z, z, z, z}, {z, z, z, z}, {z, z, z, z}, {z, z, z, z}};

  float2 st32[8];  // fp32 path: r = (t>>4) + i*16
  float2 st16[4];  // bf16 path: r = (t>>3) + i*32
  if (is32) {
#pragma unroll
    for (int i = 0; i < 8; i++) st32[i] = stats[row0 + (t >> 4) + i * 16];
  } else {
#pragma unroll
    for (int i = 0; i < 4; i++) st16[i] = stats[row0 + (t >> 3) + i * 32];
  }

  for (int kt = 0; kt < 4; kt++) {
    if (is32) {
      int c4 = t & 15;
      float gv[4], bv[4];
#pragma unroll
      for (int e = 0; e < 4; e++) {
        gv[e] = ((const float*)lng)[kt * 64 + c4 * 4 + e];
        bv[e] = ((const float*)lnb)[kt * 64 + c4 * 4 + e];
      }
#pragma unroll
      for (int i = 0; i < 8; i++) {
        int r = (t >> 4) + i * 16;
        f32x4 x = *(const f32x4*)((const float*)msa + (size_t)(row0 + r) * 256 + kt * 64 + c4 * 4);
        float mu = st32[i].x, rs = st32[i].y;
        bf16x4 y;
#pragma unroll
        for (int e = 0; e < 4; e++) y[e] = (bf16_t)((scrubf(x[e]) - mu) * rs * gv[e] + bv[e]);
        *(bf16x4*)(As + r * 72 + c4 * 4) = y;
      }
    } else {
      int c8 = t & 7;
      float gv[8], bv[8];
#pragma unroll
      for (int e = 0; e < 8; e++) {
        gv[e] = (float)((const bf16_t*)lng)[kt * 64 + c8 * 8 + e];
        bv[e] = (float)((const bf16_t*)lnb)[kt * 64 + c8 * 8 + e];
      }
#pragma unroll
      for (int i = 0; i < 4; i++) {
        int r = (t >> 3) + i * 32;
        i32x4 raw = *(const i32x4*)((const bf16_t*)msa + (size_t)(row0 + r) * 256 + kt * 64 + c8 * 8);
        const bf16_t* sp = (const bf16_t*)&raw;
        float mu = st16[i].x, rs = st16[i].y;
        bf16x8 y;
#pragma unroll
        for (int e = 0; e < 8; e++) y[e] = (bf16_t)((scrubf((float)sp[e]) - mu) * rs * gv[e] + bv[e]);
        *(bf16x8*)(As + r * 72 + c8 * 8) = y;
      }
    }
#pragma unroll
    for (int i = 0; i < 4; i++) {
      int flat = t + i * 256;  // 0..1023
      int br = flat >> 3, c8 = flat & 7;
      *(i32x4*)(Bs + br * 72 + c8 * 8) =
          *(const i32x4*)(wt_cat + (size_t)(col0 + br) * 256 + kt * 64 + c8 * 8);
    }
    __syncthreads();
#pragma unroll
    for (int kk = 0; kk < 64; kk += 32) {
      int ko = kk + (lane >> 4) * 8;
      bf16x8 a[4], b[4];
#pragma unroll
      for (int m = 0; m < 4; m++)
        a[m] = *(const bf16x8*)(As + (mw * 64 + m * 16 + (lane & 15)) * 72 + ko);
#pragma unroll
      for (int n = 0; n < 4; n++)
        b[n] = *(const bf16x8*)(Bs + (nw * 64 + n * 16 + (lane & 15)) * 72 + ko);
#pragma unroll
      for (int m = 0; m < 4; m++)
#pragma unroll
        for (int n = 0; n < 4; n++) acc[m][n] = mfma16(a[m], b[n], acc[m][n]);
    }
    __syncthreads();
  }

  int quad = lane >> 4, cl = lane & 15;
  int region = bn >> 1;  // 0:q 1:k 2:v 3:gate (uniform per block)
#pragma unroll
  for (int m = 0; m < 4; m++) {
#pragma unroll
    for (int n = 0; n < 4; n++) {
      int col = col0 + nw * 64 + n * 16 + cl;
#pragma unroll
      for (int i = 0; i < 4; i++) {
        int r = row0 + mw * 64 + m * 16 + quad * 4 + i;
        int l = r & 511;
        bool pad = (mask[l] == 0);
        float v = acc[m][n][i];
        if (region == 0) {
          qkg[(size_t)r * 768 + col] = (bf16_t)(pad ? 0.f : v);
        } else if (region == 1) {
          qkg[(size_t)r * 768 + col] = (bf16_t)(pad ? 0.f : v * SCALING);
        } else if (region == 2) {
          int hd = col & 255;
          vt[((size_t)((r >> 9) * 8 + (hd >> 5)) * 32 + (hd & 31)) * 512 + l] =
              (bf16_t)(pad ? 0.f : v);
        } else {
          int gcol = col & 255;
          float x = v + ldf(bg, gcol, is32);
          qkg[(size_t)r * 768 + 512 + gcol] = (bf16_t)(1.f / (1.f + __expf(-x)));
        }
      }
    }
  }
}

// ---------------- K4: logits[h][q][k] = sum_{n,d} q*k ----------------
__global__ __launch_bounds__(256) void k_logits(const bf16_t* qkg, float* logit_ws) {
  __shared__ bf16_t As[64 * 136];
  __shared__ bf16_t Bs[64 * 136];
  int t = threadIdx.x, lane = t & 63, w = t >> 6;
  int ktile = blockIdx.x & 7, qtile = (blockIdx.x >> 3) & 7, h = blockIdx.x >> 6;
  int mw = w & 1, nw = w >> 1;
  f32x4 z = {0.f, 0.f, 0.f, 0.f};
  f32x4 acc[2][2] = {{z, z}, {z, z}};
  for (int s = 0; s < 64; s++) {
    int kk0 = s * 128;
#pragma unroll
    for (int i = 0; i < 4; i++) {
      int flat = t + i * 256;  // 1024 chunks
      int r = flat >> 4, c8 = flat & 15;
      int kk = kk0 + c8 * 8;
      int n = kk >> 5, d = kk & 31;
      i32x4 va = *(const i32x4*)(qkg + ((size_t)(n * 512 + qtile * 64 + r)) * 768 + h * 32 + d);
      *(i32x4*)(As + r * 136 + c8 * 8) = va;
      i32x4 vb = *(const i32x4*)(qkg + ((size_t)(n * 512 + ktile * 64 + r)) * 768 + 256 + h * 32 + d);
      *(i32x4*)(Bs + r * 136 + c8 * 8) = vb;
    }
    __syncthreads();
#pragma unroll
    for (int kk = 0; kk < 128; kk += 32) {
      int ko = kk + (lane >> 4) * 8;
      bf16x8 a0 = *(const bf16x8*)(As + (mw * 32 + (lane & 15)) * 136 + ko);
      bf16x8 a1 = *(const bf16x8*)(As + (mw * 32 + 16 + (lane & 15)) * 136 + ko);
      bf16x8 b0 = *(const bf16x8*)(Bs + (nw * 32 + (lane & 15)) * 136 + ko);
      bf16x8 b1 = *(const bf16x8*)(Bs + (nw * 32 + 16 + (lane & 15)) * 136 + ko);
      acc[0][0] = mfma16(a0, b0, acc[0][0]);
      acc[0][1] = mfma16(a0, b1, acc[0][1]);
      acc[1][0] = mfma16(a1, b0, acc[1][0]);
      acc[1][1] = mfma16(a1, b1, acc[1][1]);
    }
    __syncthreads();
  }
  int quad = lane >> 4, cl = lane & 15;
#pragma unroll
  for (int mt = 0; mt < 2; mt++) {
#pragma unroll
    for (int nt = 0; nt < 2; nt++) {
      int kp = ktile * 64 + nw * 32 + nt * 16 + cl;
#pragma unroll
      for (int i = 0; i < 4; i++) {
        int q = qtile * 64 + mw * 32 + mt * 16 + quad * 4 + i;
        logit_ws[((size_t)(h * 512 + q)) * 512 + kp] = acc[mt][nt][i];
      }
    }
  }
}

// ---------------- K5: softmax over k with bias + 2D mask ----------------
__global__ __launch_bounds__(256) void k_softmax(
    const float* logit_ws, const float* bias_ws, const int* mask, bf16_t* p_ws) {
  __shared__ float red[8];
  int t = threadIdx.x;
  int hq = blockIdx.x;  // h*512 + q
  int q = hq & 511;
  bool padq = (mask[q] == 0);
  const float* lg = logit_ws + (size_t)hq * 512;
  const float* bi = bias_ws + (size_t)(hq >> 9) * 262144 + (size_t)q * 512;
  int k0 = t * 2;
  float v0 = lg[k0] + bi[k0];
  float v1 = lg[k0 + 1] + bi[k0 + 1];
  if (padq || mask[k0] == 0) v0 = -1e9f;
  if (padq || mask[k0 + 1] == 0) v1 = -1e9f;
  float m = fmaxf(v0, v1);
#pragma unroll
  for (int o = 32; o >= 1; o >>= 1) m = fmaxf(m, __shfl_xor(m, o, 64));
  if ((t & 63) == 0) red[t >> 6] = m;
  __syncthreads();
  m = fmaxf(fmaxf(red[0], red[1]), fmaxf(red[2], red[3]));
  float e0 = __expf(v0 - m), e1 = __expf(v1 - m);
  float s = e0 + e1;
#pragma unroll
  for (int o = 32; o >= 1; o >>= 1) s += __shfl_xor(s, o, 64);
  if ((t & 63) == 0) red[4 + (t >> 6)] = s;
  __syncthreads();
  s = red[4] + red[5] + red[6] + red[7];
  float inv = 1.f / s;
  p_ws[(size_t)hq * 512 + k0] = (bf16_t)(e0 * inv);
  p_ws[(size_t)hq * 512 + k0 + 1] = (bf16_t)(e1 * inv);
}

// ---------------- K6: O = P @ V, * gate -> q-region of qkg ----------------
__global__ __launch_bounds__(256) void k_av(
    const bf16_t* p_ws, const bf16_t* vt, bf16_t* qkg) {
  __shared__ bf16_t Ps[64 * 136];
  __shared__ bf16_t Vs[32 * 136];
  int t = threadIdx.x, lane = t & 63, w = t >> 6;
  int n = blockIdx.x & 255;
  int rest = blockIdx.x >> 8;
  int qt = rest & 7, h = rest >> 3;
  f32x4 z = {0.f, 0.f, 0.f, 0.f};
  f32x4 acc[2] = {z, z};
  for (int s = 0; s < 4; s++) {
    int k0 = s * 128;
#pragma unroll
    for (int i = 0; i < 4; i++) {
      int flat = t + i * 256;
      int r = flat >> 4, c8 = flat & 15;
      *(i32x4*)(Ps + r * 136 + c8 * 8) =
          *(const i32x4*)(p_ws + ((size_t)(h * 512 + qt * 64 + r)) * 512 + k0 + c8 * 8);
    }
#pragma unroll
    for (int i = 0; i < 2; i++) {
      int flat = t + i * 256;
      int r = flat >> 4, c8 = flat & 15;  // r = d
      *(i32x4*)(Vs + r * 136 + c8 * 8) =
          *(const i32x4*)(vt + ((size_t)((n * 8 + h) * 32 + r)) * 512 + k0 + c8 * 8);
    }
    __syncthreads();
#pragma unroll
    for (int kk = 0; kk < 128; kk += 32) {
      int ko = kk + (lane >> 4) * 8;
      bf16x8 a = *(const bf16x8*)(Ps + (w * 16 + (lane & 15)) * 136 + ko);
      bf16x8 b0 = *(const bf16x8*)(Vs + ((lane & 15)) * 136 + ko);
      bf16x8 b1 = *(const bf16x8*)(Vs + (16 + (lane & 15)) * 136 + ko);
      acc[0] = mfma16(a, b0, acc[0]);
      acc[1] = mfma16(a, b1, acc[1]);
    }
    __syncthreads();
  }
  int quad = lane >> 4, cl = lane & 15;
#pragma unroll
  for (int nt = 0; nt < 2; nt++) {
#pragma unroll
    for (int i = 0; i < 4; i++) {
      int q = qt * 64 + w * 16 + quad * 4 + i;
      int d = nt * 16 + cl;
      size_t base = ((size_t)(n * 512 + q)) * 768;
      float gate = (float)qkg[base + 512 + h * 32 + d];
      qkg[base + h * 32 + d] = (bf16_t)(acc[nt][i] * gate);
    }
  }
}

// ---------------- K7: out = gated @ w_out + b_out, pad-zeroed ----------------
__global__ __launch_bounds__(256) void k_out(
    const bf16_t* qkg, const bf16_t* wt_out, const void* b_out,
    const int* mask, const int* flag, void* outp) {
  __shared__ bf16_t As[64 * 72];
  __shared__ bf16_t Bs[64 * 72];
  int is32 = *flag;
  int t = threadIdx.x, lane = t & 63, w = t >> 6;
  int bm = blockIdx.x >> 2, bn = blockIdx.x & 3;
  int row0 = bm * 64;
  int mw = w & 1, nw = w >> 1;
  f32x4 z = {0.f, 0.f, 0.f, 0.f};
  f32x4 acc[2][2] = {{z, z}, {z, z}};
  for (int kt = 0; kt < 4; kt++) {
#pragma unroll
    for (int i = 0; i < 2; i++) {
      int flat = t + i * 256;
      int r = flat >> 3, c8 = flat & 7;
      *(i32x4*)(As + r * 72 + c8 * 8) =
          *(const i32x4*)(qkg + (size_t)(row0 + r) * 768 + kt * 64 + c8 * 8);
      *(i32x4*)(Bs + r * 72 + c8 * 8) =
          *(const i32x4*)(wt_out + (size_t)(bn * 64 + r) * 256 + kt * 64 + c8 * 8);
    }
    __syncthreads();
#pragma unroll
    for (int kk = 0; kk < 64; kk += 32) {
      int ko = kk + (lane >> 4) * 8;
      bf16x8 a0 = *(const bf16x8*)(As + (mw * 32 + (lane & 15)) * 72 + ko);
      bf16x8 a1 = *(const bf16x8*)(As + (mw * 32 + 16 + (lane & 15)) * 72 + ko);
      bf16x8 b0 = *(const bf16x8*)(Bs + (nw * 32 + (lane & 15)) * 72 + ko);
      bf16x8 b1 = *(const bf16x8*)(Bs + (nw * 32 + 16 + (lane & 15)) * 72 + ko);
      acc[0][0] = mfma16(a0, b0, acc[0][0]);
      acc[0][1] = mfma16(a0, b1, acc[0][1]);
      acc[1][0] = mfma16(a1, b0, acc[1][0]);
      acc[1][1] = mfma16(a1, b1, acc[1][1]);
    }
    __syncthreads();
  }
  int quad = lane >> 4, cl = lane & 15;
#pragma unroll
  for (int mt = 0; mt < 2; mt++) {
#pragma unroll
    for (int nt = 0; nt < 2; nt++) {
      int col = bn * 64 + nw * 32 + nt * 16 + cl;
      float bo = ldf(b_out, col, is32);
#pragma unroll
      for (int i = 0; i < 4; i++) {
        int r = row0 + mw * 32 + mt * 16 + quad * 4 + i;
        int l = r & 511;
        float v = acc[mt][nt][i] + bo;
        if (mask[l] == 0) v = 0.f;
        if (is32) ((float*)outp)[(size_t)r * 256 + col] = v;
        else ((bf16_t*)outp)[(size_t)r * 256 + col] = (bf16_t)v;
      }
    }
  }
}

extern "C" void kernel_launch(void* const* d_in, const int* in_sizes, int n_in,
                              void* d_out, int out_size, void* d_ws, size_t ws_size,
                              hipStream_t stream) {
  const void* msa      = d_in[0];
  const void* pair     = d_in[1];
  const void* ln_msa_g = d_in[2];
  const void* ln_msa_b = d_in[3];
  const void* ln_pair_g= d_in[4];
  const void* ln_pair_b= d_in[5];
  const void* w_q      = d_in[6];
  const void* w_k      = d_in[7];
  const void* w_v      = d_in[8];
  const void* w_b      = d_in[9];
  const void* w_g      = d_in[10];
  const void* b_g      = d_in[11];
  const void* w_out    = d_in[12];
  const void* b_out    = d_in[13];
  const int*  mask     = (const int*)d_in[14];

  char* ws = (char*)d_ws;
  bf16_t* qkg   = (bf16_t*)(ws + OFF_QKG);
  float*  logit = (float*)(ws + OFF_LOG);
  float*  biasb = (float*)(ws + OFF_BIAS);
  bf16_t* pbuf  = (bf16_t*)(ws + OFF_P);
  bf16_t* wtc   = (bf16_t*)(ws + OFF_WT);
  bf16_t* wto   = (bf16_t*)(ws + OFF_WTO);
  int*    flag  = (int*)(ws + OFF_FLAG);
  float2* stats = (float2*)(ws + OFF_STATS);
  bf16_t* vt    = (bf16_t*)d_out;  // dead before k_out writes final output

  k_detect<<<1, 256, 0, stream>>>((const unsigned short*)msa, flag);
  k_transpose<<<1280, 256, 0, stream>>>(w_q, w_k, w_v, w_g, w_out, flag, wtc, wto);
  k_stats<<<2048, 256, 0, stream>>>(msa, flag, stats);
  k_pair_bias<<<4096, 256, 0, stream>>>(pair, ln_pair_g, ln_pair_b, w_b, flag, biasb);
  k_proj<<<8192, 256, 0, stream>>>(msa, ln_msa_g, ln_msa_b, wtc, b_g, mask, flag, stats, qkg, vt);
  k_logits<<<512, 256, 0, stream>>>(qkg, logit);
  k_softmax<<<4096, 256, 0, stream>>>(logit, biasb, mask, pbuf);
  k_av<<<16384, 256, 0, stream>>>(pbuf, vt, qkg);
  k_out<<<8192, 256, 0, stream>>>(qkg, wto, b_out, mask, flag, d_out);
}